// Round 1
// baseline (341.153 us; speedup 1.0000x reference)
//
#include <hip/hip_runtime.h>

#define A_N 8192
#define OBS_D 520
#define EMB 64
#define HID 128
#define NACT 6
#define SPLIT 8

typedef short bf16x8 __attribute__((ext_vector_type(8)));
typedef float f32x4 __attribute__((ext_vector_type(4)));

__device__ inline unsigned short f2bf(float f) {
  union { float f; unsigned u; } v; v.f = f;
  unsigned u = v.u;
  u += 0x7fffu + ((u >> 16) & 1u);   // RNE
  return (unsigned short)(u >> 16);
}

__device__ inline float sigmoidf_fast(float x) {
  x = fminf(fmaxf(x, -30.f), 30.f);
  return 1.f / (1.f + __expf(-x));
}
__device__ inline float tanhf_fast(float x) {
  x = fminf(fmaxf(x, -15.f), 15.f);
  float e = __expf(-2.f * x);
  return (1.f - e) / (1.f + e);
}

// ---------------------------------------------------------------------------
// K1: h2 = relu(relu(obs@W1+b1)@W2+b2), fp32 tiled. 32 rows/block, 256 blocks.
// ---------------------------------------------------------------------------
__global__ __launch_bounds__(256) void k1_obs_mlp(
    const float* __restrict__ obs, const float* __restrict__ W1, const float* __restrict__ b1,
    const float* __restrict__ W2, const float* __restrict__ b2, float* __restrict__ h2out)
{
  __shared__ float lds_a[32][65];
  __shared__ float lds_w[64][64];
  __shared__ float lds_h1[32][65];
  const int t = threadIdx.x;
  const int r0 = blockIdx.x * 32;
  const int tr = t >> 4, tc = t & 15;   // rows tr*2+i (0..31), cols tc*4+j (0..63)

  float acc[2][4] = {};
  for (int k0 = 0; k0 < OBS_D; k0 += 64) {
    const int kc = (OBS_D - k0) < 64 ? (OBS_D - k0) : 64;
    #pragma unroll
    for (int i = 0; i < 8; i++) {
      int idx = i * 256 + t;
      int rr = idx >> 6, cc = idx & 63;
      lds_a[rr][cc] = (cc < kc) ? obs[(size_t)(r0 + rr) * OBS_D + k0 + cc] : 0.f;
    }
    #pragma unroll
    for (int i = 0; i < 16; i++) {
      int idx = i * 256 + t;
      int rr = idx >> 6, cc = idx & 63;
      lds_w[rr][cc] = (rr < kc) ? W1[(size_t)(k0 + rr) * EMB + cc] : 0.f;
    }
    __syncthreads();
    #pragma unroll 4
    for (int kk = 0; kk < 64; kk++) {
      float4 bv = *(const float4*)&lds_w[kk][tc * 4];
      #pragma unroll
      for (int i = 0; i < 2; i++) {
        float av = lds_a[tr * 2 + i][kk];
        acc[i][0] += av * bv.x; acc[i][1] += av * bv.y;
        acc[i][2] += av * bv.z; acc[i][3] += av * bv.w;
      }
    }
    __syncthreads();
  }
  // h1 = relu(acc + b1) -> LDS
  #pragma unroll
  for (int i = 0; i < 2; i++)
    #pragma unroll
    for (int j = 0; j < 4; j++)
      lds_h1[tr * 2 + i][tc * 4 + j] = fmaxf(acc[i][j] + b1[tc * 4 + j], 0.f);
  // stage W2
  #pragma unroll
  for (int i = 0; i < 16; i++) {
    int idx = i * 256 + t;
    int rr = idx >> 6, cc = idx & 63;
    lds_w[rr][cc] = W2[(size_t)rr * EMB + cc];
  }
  __syncthreads();
  float acc2[2][4] = {};
  #pragma unroll 4
  for (int kk = 0; kk < 64; kk++) {
    float4 bv = *(const float4*)&lds_w[kk][tc * 4];
    #pragma unroll
    for (int i = 0; i < 2; i++) {
      float av = lds_h1[tr * 2 + i][kk];
      acc2[i][0] += av * bv.x; acc2[i][1] += av * bv.y;
      acc2[i][2] += av * bv.z; acc2[i][3] += av * bv.w;
    }
  }
  #pragma unroll
  for (int i = 0; i < 2; i++) {
    float4 o;
    o.x = fmaxf(acc2[i][0] + b2[tc * 4 + 0], 0.f);
    o.y = fmaxf(acc2[i][1] + b2[tc * 4 + 1], 0.f);
    o.z = fmaxf(acc2[i][2] + b2[tc * 4 + 2], 0.f);
    o.w = fmaxf(acc2[i][3] + b2[tc * 4 + 3], 0.f);
    *(float4*)&h2out[(size_t)(r0 + tr * 2 + i) * EMB + tc * 4] = o;
  }
}

// ---------------------------------------------------------------------------
// K2a: bp = beliefs@Wb+bb -> bf16 row-major [8192][64] and bf16 transposed [64][8192]
// ---------------------------------------------------------------------------
__global__ __launch_bounds__(256) void k2a_bp(
    const float* __restrict__ beliefs, const float* __restrict__ Wb, const float* __restrict__ bb,
    unsigned short* __restrict__ bp, unsigned short* __restrict__ bpT)
{
  __shared__ float lds_a[32][65];
  __shared__ float lds_w[64][64];
  __shared__ float lds_o[32][65];
  const int t = threadIdx.x;
  const int r0 = blockIdx.x * 32;
  const int tr = t >> 4, tc = t & 15;

  float acc[2][4] = {};
  for (int k0 = 0; k0 < HID; k0 += 64) {
    #pragma unroll
    for (int i = 0; i < 8; i++) {
      int idx = i * 256 + t;
      int rr = idx >> 6, cc = idx & 63;
      lds_a[rr][cc] = beliefs[(size_t)(r0 + rr) * HID + k0 + cc];
    }
    #pragma unroll
    for (int i = 0; i < 16; i++) {
      int idx = i * 256 + t;
      int rr = idx >> 6, cc = idx & 63;
      lds_w[rr][cc] = Wb[(size_t)(k0 + rr) * EMB + cc];
    }
    __syncthreads();
    #pragma unroll 4
    for (int kk = 0; kk < 64; kk++) {
      float4 bv = *(const float4*)&lds_w[kk][tc * 4];
      #pragma unroll
      for (int i = 0; i < 2; i++) {
        float av = lds_a[tr * 2 + i][kk];
        acc[i][0] += av * bv.x; acc[i][1] += av * bv.y;
        acc[i][2] += av * bv.z; acc[i][3] += av * bv.w;
      }
    }
    __syncthreads();
  }
  #pragma unroll
  for (int i = 0; i < 2; i++)
    #pragma unroll
    for (int j = 0; j < 4; j++)
      lds_o[tr * 2 + i][tc * 4 + j] = acc[i][j] + bb[tc * 4 + j];
  __syncthreads();
  // row-major bf16 (coalesced)
  #pragma unroll
  for (int i = 0; i < 8; i++) {
    int idx = i * 256 + t;
    int rr = idx >> 6, cc = idx & 63;
    bp[(size_t)(r0 + rr) * EMB + cc] = f2bf(lds_o[rr][cc]);
  }
  // transposed bf16 (coalesced along r)
  #pragma unroll
  for (int i = 0; i < 8; i++) {
    int idx = i * 256 + t;
    int c = idx >> 5, r = idx & 31;
    bpT[(size_t)c * A_N + r0 + r] = f2bf(lds_o[r][c]);
  }
}

// ---------------------------------------------------------------------------
// K2b: flash attention, bf16 MFMA 16x16x32.
// wave = (qtile of 16 rows) x (key split of A_N/SPLIT keys). Unnormalized
// exp-accumulation (logits bounded, no max-rescale needed).
// A-frag: A[m=lane&15][k=(lane>>4)*8+j]   B-frag: B[k=(lane>>4)*8+j][n=lane&15]
// C/D:    D[(lane>>4)*4+r][lane&15]
// ---------------------------------------------------------------------------
__global__ __launch_bounds__(256) void k2b_attn(
    const unsigned short* __restrict__ bp, const unsigned short* __restrict__ bpT,
    float* __restrict__ ctxp, float* __restrict__ sums)
{
  __shared__ unsigned short P[4][16 * 72];  // wave-private P buffers, stride 72 (16B-aligned rows)
  const int lane = threadIdx.x & 63;
  const int wid = threadIdx.x >> 6;
  const int w = blockIdx.x * 4 + wid;
  const int split = w >> 9;       // split-major: co-resident waves share key tiles
  const int qtile = w & 511;
  const int q0 = qtile * 16;
  const int m = lane & 15, quad = lane >> 4;

  const bf16x8 qa0 = *(const bf16x8*)(bp + (size_t)(q0 + m) * EMB + quad * 8);
  const bf16x8 qa1 = *(const bf16x8*)(bp + (size_t)(q0 + m) * EMB + 32 + quad * 8);

  f32x4 oacc[4];
  #pragma unroll
  for (int d = 0; d < 4; d++) oacc[d] = (f32x4){0.f, 0.f, 0.f, 0.f};
  float rowsum[4] = {0.f, 0.f, 0.f, 0.f};

  unsigned short* Pl = &P[wid][0];
  const int kbeg = split * (A_N / SPLIT);
  const int kend = kbeg + (A_N / SPLIT);

  for (int k0 = kbeg; k0 < kend; k0 += 64) {
    float pv[4][4];
    #pragma unroll
    for (int jt = 0; jt < 4; jt++) {
      const unsigned short* kr = bp + (size_t)(k0 + jt * 16 + m) * EMB + quad * 8;
      const bf16x8 kb0 = *(const bf16x8*)(kr);
      const bf16x8 kb1 = *(const bf16x8*)(kr + 32);
      f32x4 s = (f32x4){0.f, 0.f, 0.f, 0.f};
      s = __builtin_amdgcn_mfma_f32_16x16x32_bf16(qa0, kb0, s, 0, 0, 0);
      s = __builtin_amdgcn_mfma_f32_16x16x32_bf16(qa1, kb1, s, 0, 0, 0);
      const int gj = k0 + jt * 16 + m;
      #pragma unroll
      for (int r = 0; r < 4; r++) {
        const int gi = q0 + quad * 4 + r;
        float p = (gi == gj) ? 0.f : __expf(s[r] * 0.125f);
        pv[jt][r] = p;
        rowsum[r] += p;
      }
    }
    // P: C-layout -> LDS (row-major 16x64, stride 72)
    #pragma unroll
    for (int jt = 0; jt < 4; jt++)
      #pragma unroll
      for (int r = 0; r < 4; r++)
        Pl[(quad * 4 + r) * 72 + jt * 16 + m] = f2bf(pv[jt][r]);
    __syncthreads();   // all waves have identical trip count; orders write->read
    const bf16x8 pa0 = *(const bf16x8*)(Pl + m * 72 + quad * 8);        // j = 0..31
    const bf16x8 pa1 = *(const bf16x8*)(Pl + m * 72 + 32 + quad * 8);   // j = 32..63
    #pragma unroll
    for (int dt = 0; dt < 4; dt++) {
      const unsigned short* vr = bpT + (size_t)(dt * 16 + m) * A_N + k0 + quad * 8;
      const bf16x8 vb0 = *(const bf16x8*)(vr);
      const bf16x8 vb1 = *(const bf16x8*)(vr + 32);
      oacc[dt] = __builtin_amdgcn_mfma_f32_16x16x32_bf16(pa0, vb0, oacc[dt], 0, 0, 0);
      oacc[dt] = __builtin_amdgcn_mfma_f32_16x16x32_bf16(pa1, vb1, oacc[dt], 0, 0, 0);
    }
    __syncthreads();   // reads done before next iteration's writes
  }

  // reduce rowsum across the 16 lanes sharing each row (xor within quad group)
  #pragma unroll
  for (int r = 0; r < 4; r++) {
    float v = rowsum[r];
    v += __shfl_xor(v, 1, 64);
    v += __shfl_xor(v, 2, 64);
    v += __shfl_xor(v, 4, 64);
    v += __shfl_xor(v, 8, 64);
    rowsum[r] = v;
  }
  const size_t base = ((size_t)split * A_N + q0) * EMB;
  #pragma unroll
  for (int dt = 0; dt < 4; dt++)
    #pragma unroll
    for (int r = 0; r < 4; r++)
      ctxp[base + (size_t)(quad * 4 + r) * EMB + dt * 16 + m] = oacc[dt][r];
  if (m == 0) {
    #pragma unroll
    for (int r = 0; r < 4; r++)
      sums[(size_t)split * A_N + q0 + quad * 4 + r] = rowsum[r];
  }
}

// ---------------------------------------------------------------------------
// K3: fused GRU + logits, fp32. 16 rows/block, 512 blocks.
// ---------------------------------------------------------------------------
__global__ __launch_bounds__(256) void k3_gru(
    const float* __restrict__ beliefs, const float* __restrict__ h2,
    const float* __restrict__ ctxp, const float* __restrict__ sums,
    const float* __restrict__ Wg, const float* __restrict__ bg,
    const float* __restrict__ Wir, const float* __restrict__ Wiz, const float* __restrict__ Win,
    const float* __restrict__ Whr, const float* __restrict__ bhr,
    const float* __restrict__ Whz, const float* __restrict__ bhz,
    const float* __restrict__ Whn, const float* __restrict__ bhn,
    const float* __restrict__ Wout, const float* __restrict__ bout,
    float* __restrict__ out)
{
  __shared__ float lds_x[16][129];     // x = [h2 | ctx], later reused for new_beliefs
  __shared__ float lds_g[16][129];     // gru_in
  __shared__ float lds_w[32 * 128];    // weight chunk (also holds Wout at the end)
  __shared__ float lds_b[16][33];      // beliefs chunk
  __shared__ float lds_bo[8];
  const int t = threadIdx.x;
  const int r0 = blockIdx.x * 16;
  const int tr = t >> 5, tc = t & 31;  // rows tr*2+i (0..15), cols tc*4+j (0..127)

  // 1. build x
  #pragma unroll
  for (int i = 0; i < 8; i++) {
    int idx = i * 256 + t;
    int rr = idx >> 7, cc = idx & 127;
    float v;
    if (cc < 64) {
      v = h2[(size_t)(r0 + rr) * EMB + cc];
    } else {
      float cs = 0.f, ss = 0.f;
      #pragma unroll
      for (int sp = 0; sp < SPLIT; sp++) {
        cs += ctxp[((size_t)sp * A_N + r0 + rr) * EMB + (cc - 64)];
        ss += sums[(size_t)sp * A_N + r0 + rr];
      }
      v = cs / ss;
    }
    lds_x[rr][cc] = v;
  }
  __syncthreads();

  // 2. gru_in = x @ Wg + bg
  float acc[2][4] = {};
  for (int k0 = 0; k0 < HID; k0 += 32) {
    #pragma unroll
    for (int i = 0; i < 16; i++) {
      int idx = i * 256 + t;
      int rr = idx >> 7, cc = idx & 127;
      lds_w[idx] = Wg[(size_t)(k0 + rr) * HID + cc];
    }
    __syncthreads();
    #pragma unroll 4
    for (int kk = 0; kk < 32; kk++) {
      float4 bv = *(const float4*)&lds_w[kk * 128 + tc * 4];
      #pragma unroll
      for (int i = 0; i < 2; i++) {
        float av = lds_x[tr * 2 + i][k0 + kk];
        acc[i][0] += av * bv.x; acc[i][1] += av * bv.y;
        acc[i][2] += av * bv.z; acc[i][3] += av * bv.w;
      }
    }
    __syncthreads();
  }
  #pragma unroll
  for (int i = 0; i < 2; i++)
    #pragma unroll
    for (int j = 0; j < 4; j++)
      lds_g[tr * 2 + i][tc * 4 + j] = acc[i][j] + bg[tc * 4 + j];
  __syncthreads();

  // 3. gates
  const float* Wi_arr[3] = {Wir, Wiz, Win};
  const float* Wh_arr[3] = {Whr, Whz, Whn};
  float rv[2][4], zv[2][4], nb[2][4];
  #pragma unroll
  for (int g = 0; g < 3; g++) {
    float gi[2][4] = {}, gh[2][4] = {};
    for (int k0 = 0; k0 < HID; k0 += 32) {
      // input-side chunk
      #pragma unroll
      for (int i = 0; i < 16; i++) {
        int idx = i * 256 + t;
        int rr = idx >> 7, cc = idx & 127;
        lds_w[idx] = Wi_arr[g][(size_t)(k0 + rr) * HID + cc];
      }
      __syncthreads();
      #pragma unroll 4
      for (int kk = 0; kk < 32; kk++) {
        float4 bv = *(const float4*)&lds_w[kk * 128 + tc * 4];
        #pragma unroll
        for (int i = 0; i < 2; i++) {
          float av = lds_g[tr * 2 + i][k0 + kk];
          gi[i][0] += av * bv.x; gi[i][1] += av * bv.y;
          gi[i][2] += av * bv.z; gi[i][3] += av * bv.w;
        }
      }
      __syncthreads();
      // hidden-side chunk
      #pragma unroll
      for (int i = 0; i < 16; i++) {
        int idx = i * 256 + t;
        int rr = idx >> 7, cc = idx & 127;
        lds_w[idx] = Wh_arr[g][(size_t)(k0 + rr) * HID + cc];
      }
      #pragma unroll
      for (int i = 0; i < 2; i++) {
        int idx = i * 256 + t;
        int rr = idx >> 5, cc = idx & 31;
        lds_b[rr][cc] = beliefs[(size_t)(r0 + rr) * HID + k0 + cc];
      }
      __syncthreads();
      #pragma unroll 4
      for (int kk = 0; kk < 32; kk++) {
        float4 bv = *(const float4*)&lds_w[kk * 128 + tc * 4];
        #pragma unroll
        for (int i = 0; i < 2; i++) {
          float av = lds_b[tr * 2 + i][kk];
          gh[i][0] += av * bv.x; gh[i][1] += av * bv.y;
          gh[i][2] += av * bv.z; gh[i][3] += av * bv.w;
        }
      }
      __syncthreads();
    }
    if (g == 0) {
      #pragma unroll
      for (int i = 0; i < 2; i++)
        #pragma unroll
        for (int j = 0; j < 4; j++)
          rv[i][j] = sigmoidf_fast(gi[i][j] + gh[i][j] + bhr[tc * 4 + j]);
    } else if (g == 1) {
      #pragma unroll
      for (int i = 0; i < 2; i++)
        #pragma unroll
        for (int j = 0; j < 4; j++)
          zv[i][j] = sigmoidf_fast(gi[i][j] + gh[i][j] + bhz[tc * 4 + j]);
    } else {
      #pragma unroll
      for (int i = 0; i < 2; i++) {
        float4 bel = *(const float4*)&beliefs[(size_t)(r0 + tr * 2 + i) * HID + tc * 4];
        float b4[4] = {bel.x, bel.y, bel.z, bel.w};
        #pragma unroll
        for (int j = 0; j < 4; j++) {
          float pre = gi[i][j] + rv[i][j] * (gh[i][j] + bhn[tc * 4 + j]);
          float nv = tanhf_fast(pre);
          nb[i][j] = (1.f - zv[i][j]) * nv + zv[i][j] * b4[j];
        }
      }
    }
  }

  // write new_beliefs; stash in lds_x for logits
  #pragma unroll
  for (int i = 0; i < 2; i++) {
    float4 o = {nb[i][0], nb[i][1], nb[i][2], nb[i][3]};
    *(float4*)&out[(size_t)NACT * A_N + (size_t)(r0 + tr * 2 + i) * HID + tc * 4] = o;
    #pragma unroll
    for (int j = 0; j < 4; j++)
      lds_x[tr * 2 + i][tc * 4 + j] = nb[i][j];
  }
  // stage Wout/bout
  for (int idx = t; idx < HID * NACT; idx += 256) lds_w[idx] = Wout[idx];
  if (t < NACT) lds_bo[t] = bout[t];
  __syncthreads();
  // logits
  if (t < 16 * NACT) {
    int r = t / NACT, c = t % NACT;
    float a = lds_bo[c];
    #pragma unroll 4
    for (int k = 0; k < HID; k++) a += lds_x[r][k] * lds_w[k * NACT + c];
    out[(size_t)(r0 + r) * NACT + c] = a;
  }
}

// ---------------------------------------------------------------------------
extern "C" void kernel_launch(void* const* d_in, const int* in_sizes, int n_in,
                              void* d_out, int out_size, void* d_ws, size_t ws_size,
                              hipStream_t stream) {
  const float* obs     = (const float*)d_in[0];
  const float* beliefs = (const float*)d_in[1];
  const float* W1      = (const float*)d_in[2];
  const float* b1      = (const float*)d_in[3];
  const float* W2      = (const float*)d_in[4];
  const float* b2      = (const float*)d_in[5];
  const float* Wb      = (const float*)d_in[6];
  const float* bb      = (const float*)d_in[7];
  const float* Wg      = (const float*)d_in[8];
  const float* bg      = (const float*)d_in[9];
  const float* Wir     = (const float*)d_in[10];
  const float* Wiz     = (const float*)d_in[11];
  const float* Win     = (const float*)d_in[12];
  const float* Whr     = (const float*)d_in[13];
  const float* bhr     = (const float*)d_in[14];
  const float* Whz     = (const float*)d_in[15];
  const float* bhz     = (const float*)d_in[16];
  const float* Whn     = (const float*)d_in[17];
  const float* bhn     = (const float*)d_in[18];
  const float* Wout    = (const float*)d_in[19];
  const float* bout    = (const float*)d_in[20];
  float* out = (float*)d_out;

  // workspace layout (bytes): h2 2MB | bp 1MB | bpT 1MB | ctxp 16MB | sums 256KB
  char* ws = (char*)d_ws;
  float*          h2   = (float*)(ws);
  unsigned short* bp   = (unsigned short*)(ws + 2097152);
  unsigned short* bpT  = (unsigned short*)(ws + 3145728);
  float*          ctxp = (float*)(ws + 4194304);
  float*          sums = (float*)(ws + 4194304 + 16777216);

  hipLaunchKernelGGL(k1_obs_mlp, dim3(256), dim3(256), 0, stream, obs, W1, b1, W2, b2, h2);
  hipLaunchKernelGGL(k2a_bp, dim3(256), dim3(256), 0, stream, beliefs, Wb, bb, bp, bpT);
  hipLaunchKernelGGL(k2b_attn, dim3((A_N / 16) * SPLIT / 4), dim3(256), 0, stream, bp, bpT, ctxp, sums);
  hipLaunchKernelGGL(k3_gru, dim3(A_N / 16), dim3(256), 0, stream, beliefs, h2, ctxp, sums,
                     Wg, bg, Wir, Wiz, Win, Whr, bhr, Whz, bhz, Whn, bhn, Wout, bout, out);
}

// Round 2
// 307.400 us; speedup vs baseline: 1.1098x; 1.1098x over previous
//
#include <hip/hip_runtime.h>

#define A_N 8192
#define OBS_D 520
#define EMB 64
#define HID 128
#define NACT 6
#define SPLIT 16
#define QROWS 32

typedef short bf16x8 __attribute__((ext_vector_type(8)));
typedef float f32x4 __attribute__((ext_vector_type(4)));

__device__ inline unsigned short f2bf(float f) {
  union { float f; unsigned u; } v; v.f = f;
  unsigned u = v.u;
  u += 0x7fffu + ((u >> 16) & 1u);   // RNE
  return (unsigned short)(u >> 16);
}
__device__ inline float b2f(unsigned short u) {
  union { unsigned u; float f; } v; v.u = ((unsigned)u) << 16; return v.f;
}

__device__ inline float sigmoidf_fast(float x) {
  x = fminf(fmaxf(x, -30.f), 30.f);
  return 1.f / (1.f + __expf(-x));
}
__device__ inline float tanhf_fast(float x) {
  x = fminf(fmaxf(x, -15.f), 15.f);
  float e = __expf(-2.f * x);
  return (1.f - e) / (1.f + e);
}

// ---------------------------------------------------------------------------
// K1: h2 = relu(relu(obs@W1+b1)@W2+b2), fp32 tiled.
// 16 rows/block, 512 blocks = 2 blocks/CU = 8 waves/CU (was 1 block/CU).
// ---------------------------------------------------------------------------
__global__ __launch_bounds__(256) void k1_obs_mlp(
    const float* __restrict__ obs, const float* __restrict__ W1, const float* __restrict__ b1,
    const float* __restrict__ W2, const float* __restrict__ b2, float* __restrict__ h2out)
{
  __shared__ float lds_a[16][65];
  __shared__ float lds_w[64][64];
  __shared__ float lds_h1[16][65];
  const int t = threadIdx.x;
  const int r0 = blockIdx.x * 16;
  const int row = t >> 4;        // 0..15
  const int tcol = t & 15;       // cols tcol*4 .. +3

  float acc[4] = {};
  for (int k0 = 0; k0 < OBS_D; k0 += 64) {
    const int kc = (OBS_D - k0) < 64 ? (OBS_D - k0) : 64;
    {
      const int cc = tcol * 4;
      #pragma unroll
      for (int j = 0; j < 4; j++)
        lds_a[row][cc + j] = (cc + j < kc) ? obs[(size_t)(r0 + row) * OBS_D + k0 + cc + j] : 0.f;
    }
    #pragma unroll
    for (int i = 0; i < 16; i++) {
      int idx = i * 256 + t;
      int rr = idx >> 6, cc = idx & 63;
      lds_w[rr][cc] = (rr < kc) ? W1[(size_t)(k0 + rr) * EMB + cc] : 0.f;
    }
    __syncthreads();
    #pragma unroll 8
    for (int kk = 0; kk < 64; kk++) {
      float4 bv = *(const float4*)&lds_w[kk][tcol * 4];
      float av = lds_a[row][kk];
      acc[0] += av * bv.x; acc[1] += av * bv.y;
      acc[2] += av * bv.z; acc[3] += av * bv.w;
    }
    __syncthreads();
  }
  #pragma unroll
  for (int j = 0; j < 4; j++)
    lds_h1[row][tcol * 4 + j] = fmaxf(acc[j] + b1[tcol * 4 + j], 0.f);
  #pragma unroll
  for (int i = 0; i < 16; i++) {
    int idx = i * 256 + t;
    int rr = idx >> 6, cc = idx & 63;
    lds_w[rr][cc] = W2[(size_t)rr * EMB + cc];
  }
  __syncthreads();
  float acc2[4] = {};
  #pragma unroll 8
  for (int kk = 0; kk < 64; kk++) {
    float4 bv = *(const float4*)&lds_w[kk][tcol * 4];
    float av = lds_h1[row][kk];
    acc2[0] += av * bv.x; acc2[1] += av * bv.y;
    acc2[2] += av * bv.z; acc2[3] += av * bv.w;
  }
  float4 o;
  o.x = fmaxf(acc2[0] + b2[tcol * 4 + 0], 0.f);
  o.y = fmaxf(acc2[1] + b2[tcol * 4 + 1], 0.f);
  o.z = fmaxf(acc2[2] + b2[tcol * 4 + 2], 0.f);
  o.w = fmaxf(acc2[3] + b2[tcol * 4 + 3], 0.f);
  *(float4*)&h2out[(size_t)(r0 + row) * EMB + tcol * 4] = o;
}

// ---------------------------------------------------------------------------
// K2a: bp = beliefs@Wb+bb -> bf16 row-major [8192][64] and bf16 transposed [64][8192]
// (unchanged from round 1 — small kernel, known correct)
// ---------------------------------------------------------------------------
__global__ __launch_bounds__(256) void k2a_bp(
    const float* __restrict__ beliefs, const float* __restrict__ Wb, const float* __restrict__ bb,
    unsigned short* __restrict__ bp, unsigned short* __restrict__ bpT)
{
  __shared__ float lds_a[32][65];
  __shared__ float lds_w[64][64];
  __shared__ float lds_o[32][65];
  const int t = threadIdx.x;
  const int r0 = blockIdx.x * 32;
  const int tr = t >> 4, tc = t & 15;

  float acc[2][4] = {};
  for (int k0 = 0; k0 < HID; k0 += 64) {
    #pragma unroll
    for (int i = 0; i < 8; i++) {
      int idx = i * 256 + t;
      int rr = idx >> 6, cc = idx & 63;
      lds_a[rr][cc] = beliefs[(size_t)(r0 + rr) * HID + k0 + cc];
    }
    #pragma unroll
    for (int i = 0; i < 16; i++) {
      int idx = i * 256 + t;
      int rr = idx >> 6, cc = idx & 63;
      lds_w[rr][cc] = Wb[(size_t)(k0 + rr) * EMB + cc];
    }
    __syncthreads();
    #pragma unroll 4
    for (int kk = 0; kk < 64; kk++) {
      float4 bv = *(const float4*)&lds_w[kk][tc * 4];
      #pragma unroll
      for (int i = 0; i < 2; i++) {
        float av = lds_a[tr * 2 + i][kk];
        acc[i][0] += av * bv.x; acc[i][1] += av * bv.y;
        acc[i][2] += av * bv.z; acc[i][3] += av * bv.w;
      }
    }
    __syncthreads();
  }
  #pragma unroll
  for (int i = 0; i < 2; i++)
    #pragma unroll
    for (int j = 0; j < 4; j++)
      lds_o[tr * 2 + i][tc * 4 + j] = acc[i][j] + bb[tc * 4 + j];
  __syncthreads();
  #pragma unroll
  for (int i = 0; i < 8; i++) {
    int idx = i * 256 + t;
    int rr = idx >> 6, cc = idx & 63;
    bp[(size_t)(r0 + rr) * EMB + cc] = f2bf(lds_o[rr][cc]);
  }
  #pragma unroll
  for (int i = 0; i < 8; i++) {
    int idx = i * 256 + t;
    int c = idx >> 5, r = idx & 31;
    bpT[(size_t)c * A_N + r0 + r] = f2bf(lds_o[r][c]);
  }
}

// ---------------------------------------------------------------------------
// K2b: flash attention, bf16 MFMA 16x16x32 — BARRIER-FREE.
// wave = 32 Q rows (2 A-frags) x one key split (512 keys, 8 tiles of 64).
// P buffers are wave-private: within-wave DS ordering (in-order LDS pipeline)
// + s_waitcnt lgkmcnt(0) replaces __syncthreads, so global loads stay in
// flight across iterations (no vmcnt(0) drain).
// SPLIT=16 -> 4096 waves = 16 waves/CU.
// ---------------------------------------------------------------------------
__global__ __launch_bounds__(256) void k2b_attn(
    const unsigned short* __restrict__ bp, const unsigned short* __restrict__ bpT,
    unsigned short* __restrict__ ctxp, unsigned short* __restrict__ sums)
{
  __shared__ __align__(16) unsigned short P[4][2][16 * 72];  // per-wave, per-Qfrag; row stride 144B (16B-mult)
  const int lane = threadIdx.x & 63;
  const int wid = threadIdx.x >> 6;
  const int w = blockIdx.x * 4 + wid;
  const int split = w >> 8;          // 256 waves per split: co-resident waves stream same keys
  const int qt = w & 255;
  const int q0 = qt * QROWS;
  const int m = lane & 15, quad = lane >> 4;

  bf16x8 qa[2][2];
  #pragma unroll
  for (int f = 0; f < 2; f++) {
    const unsigned short* qr = bp + (size_t)(q0 + f * 16 + m) * EMB + quad * 8;
    qa[f][0] = *(const bf16x8*)(qr);
    qa[f][1] = *(const bf16x8*)(qr + 32);
  }

  f32x4 oacc[2][4];
  #pragma unroll
  for (int f = 0; f < 2; f++)
    #pragma unroll
    for (int d = 0; d < 4; d++) oacc[f][d] = (f32x4){0.f, 0.f, 0.f, 0.f};
  float rowsum[2][4] = {};

  const int kbeg = split * (A_N / SPLIT);
  const int kend = kbeg + (A_N / SPLIT);

  for (int k0 = kbeg; k0 < kend; k0 += 64) {
    // QK^T + exp + P-write (wave-private LDS)
    #pragma unroll
    for (int jt = 0; jt < 4; jt++) {
      const unsigned short* kr = bp + (size_t)(k0 + jt * 16 + m) * EMB + quad * 8;
      const bf16x8 kb0 = *(const bf16x8*)(kr);
      const bf16x8 kb1 = *(const bf16x8*)(kr + 32);
      const int gj = k0 + jt * 16 + m;
      #pragma unroll
      for (int f = 0; f < 2; f++) {
        f32x4 s = (f32x4){0.f, 0.f, 0.f, 0.f};
        s = __builtin_amdgcn_mfma_f32_16x16x32_bf16(qa[f][0], kb0, s, 0, 0, 0);
        s = __builtin_amdgcn_mfma_f32_16x16x32_bf16(qa[f][1], kb1, s, 0, 0, 0);
        #pragma unroll
        for (int r = 0; r < 4; r++) {
          const int gi = q0 + f * 16 + quad * 4 + r;
          float p = (gi == gj) ? 0.f : __expf(s[r] * 0.125f);
          rowsum[f][r] += p;
          P[wid][f][(quad * 4 + r) * 72 + jt * 16 + m] = f2bf(p);
        }
      }
    }
    // V loads issued now: in flight while the LDS transform completes
    bf16x8 vb[4][2];
    #pragma unroll
    for (int dt = 0; dt < 4; dt++) {
      const unsigned short* vr = bpT + (size_t)(dt * 16 + m) * A_N + k0 + quad * 8;
      vb[dt][0] = *(const bf16x8*)(vr);
      vb[dt][1] = *(const bf16x8*)(vr + 32);
    }
    // wave-local ordering of ds_write -> ds_read (no block barrier!)
    asm volatile("s_waitcnt lgkmcnt(0)" ::: "memory");
    bf16x8 pa[2][2];
    #pragma unroll
    for (int f = 0; f < 2; f++) {
      pa[f][0] = *(const bf16x8*)&P[wid][f][m * 72 + quad * 8];
      pa[f][1] = *(const bf16x8*)&P[wid][f][m * 72 + 32 + quad * 8];
    }
    #pragma unroll
    for (int dt = 0; dt < 4; dt++)
      #pragma unroll
      for (int f = 0; f < 2; f++) {
        oacc[f][dt] = __builtin_amdgcn_mfma_f32_16x16x32_bf16(pa[f][0], vb[dt][0], oacc[f][dt], 0, 0, 0);
        oacc[f][dt] = __builtin_amdgcn_mfma_f32_16x16x32_bf16(pa[f][1], vb[dt][1], oacc[f][dt], 0, 0, 0);
      }
  }

  // reduce rowsum across the 16 lanes sharing each row
  #pragma unroll
  for (int f = 0; f < 2; f++)
    #pragma unroll
    for (int r = 0; r < 4; r++) {
      float v = rowsum[f][r];
      v += __shfl_xor(v, 1, 64);
      v += __shfl_xor(v, 2, 64);
      v += __shfl_xor(v, 4, 64);
      v += __shfl_xor(v, 8, 64);
      rowsum[f][r] = v;
    }
  #pragma unroll
  for (int f = 0; f < 2; f++) {
    const size_t base = ((size_t)split * A_N + q0 + f * 16) * EMB;
    #pragma unroll
    for (int dt = 0; dt < 4; dt++)
      #pragma unroll
      for (int r = 0; r < 4; r++)
        ctxp[base + (size_t)(quad * 4 + r) * EMB + dt * 16 + m] = f2bf(oacc[f][dt][r]);
    if (m == 0) {
      #pragma unroll
      for (int r = 0; r < 4; r++)
        sums[(size_t)split * A_N + q0 + f * 16 + quad * 4 + r] = f2bf(rowsum[f][r]);
    }
  }
}

// ---------------------------------------------------------------------------
// K3: fused GRU + logits, fp32. 8 rows/block, 1024 blocks = 4/CU = 16 waves/CU.
// ---------------------------------------------------------------------------
__global__ __launch_bounds__(256) void k3_gru(
    const float* __restrict__ beliefs, const float* __restrict__ h2,
    const unsigned short* __restrict__ ctxp, const unsigned short* __restrict__ sums,
    const float* __restrict__ Wg, const float* __restrict__ bg,
    const float* __restrict__ Wir, const float* __restrict__ Wiz, const float* __restrict__ Win,
    const float* __restrict__ Whr, const float* __restrict__ bhr,
    const float* __restrict__ Whz, const float* __restrict__ bhz,
    const float* __restrict__ Whn, const float* __restrict__ bhn,
    const float* __restrict__ Wout, const float* __restrict__ bout,
    float* __restrict__ out)
{
  __shared__ float lds_x[8][129];     // x = [h2 | ctx]; reused for new_beliefs
  __shared__ float lds_g[8][129];     // gru_in
  __shared__ float lds_w[32 * 128];   // weight chunk (also Wout at end)
  __shared__ float lds_b[8][33];      // beliefs chunk
  __shared__ float lds_ss[8];
  __shared__ float lds_bo[8];
  const int t = threadIdx.x;
  const int r0 = blockIdx.x * 8;
  const int row = t >> 5;             // 0..7 (one row per thread-group of 32)
  const int tc = t & 31;              // cols tc*4 .. +3

  if (t < 8) {
    float ss = 0.f;
    #pragma unroll
    for (int sp = 0; sp < SPLIT; sp++) ss += b2f(sums[(size_t)sp * A_N + r0 + t]);
    lds_ss[t] = ss;
  }
  __syncthreads();

  // build x = [h2 | ctx]; 4 contiguous elems per thread
  {
    const int cc = tc * 4;
    if (cc < 64) {
      float4 h = *(const float4*)&h2[(size_t)(r0 + row) * EMB + cc];
      lds_x[row][cc + 0] = h.x; lds_x[row][cc + 1] = h.y;
      lds_x[row][cc + 2] = h.z; lds_x[row][cc + 3] = h.w;
    } else {
      float cs[4] = {};
      #pragma unroll
      for (int sp = 0; sp < SPLIT; sp++) {
        ushort4 u = *(const ushort4*)&ctxp[((size_t)sp * A_N + r0 + row) * EMB + (cc - 64)];
        cs[0] += b2f(u.x); cs[1] += b2f(u.y); cs[2] += b2f(u.z); cs[3] += b2f(u.w);
      }
      const float inv = 1.f / lds_ss[row];
      #pragma unroll
      for (int j = 0; j < 4; j++) lds_x[row][cc + j] = cs[j] * inv;
    }
  }
  __syncthreads();

  // gru_in = x @ Wg + bg
  float acc[4] = {};
  for (int k0 = 0; k0 < HID; k0 += 32) {
    #pragma unroll
    for (int i = 0; i < 16; i++) {
      int idx = i * 256 + t;
      lds_w[idx] = Wg[(size_t)(k0 + (idx >> 7)) * HID + (idx & 127)];
    }
    __syncthreads();
    #pragma unroll 8
    for (int kk = 0; kk < 32; kk++) {
      float4 bv = *(const float4*)&lds_w[kk * 128 + tc * 4];
      float av = lds_x[row][k0 + kk];
      acc[0] += av * bv.x; acc[1] += av * bv.y;
      acc[2] += av * bv.z; acc[3] += av * bv.w;
    }
    __syncthreads();
  }
  #pragma unroll
  for (int j = 0; j < 4; j++)
    lds_g[row][tc * 4 + j] = acc[j] + bg[tc * 4 + j];
  __syncthreads();

  const float* Wi_arr[3] = {Wir, Wiz, Win};
  const float* Wh_arr[3] = {Whr, Whz, Whn};
  float rv[4], zv[4], nb[4];
  #pragma unroll
  for (int g = 0; g < 3; g++) {
    float gi[4] = {}, gh[4] = {};
    for (int k0 = 0; k0 < HID; k0 += 32) {
      #pragma unroll
      for (int i = 0; i < 16; i++) {
        int idx = i * 256 + t;
        lds_w[idx] = Wi_arr[g][(size_t)(k0 + (idx >> 7)) * HID + (idx & 127)];
      }
      __syncthreads();
      #pragma unroll 8
      for (int kk = 0; kk < 32; kk++) {
        float4 bv = *(const float4*)&lds_w[kk * 128 + tc * 4];
        float av = lds_g[row][k0 + kk];
        gi[0] += av * bv.x; gi[1] += av * bv.y;
        gi[2] += av * bv.z; gi[3] += av * bv.w;
      }
      __syncthreads();
      #pragma unroll
      for (int i = 0; i < 16; i++) {
        int idx = i * 256 + t;
        lds_w[idx] = Wh_arr[g][(size_t)(k0 + (idx >> 7)) * HID + (idx & 127)];
      }
      lds_b[row][tc] = beliefs[(size_t)(r0 + row) * HID + k0 + tc];
      __syncthreads();
      #pragma unroll 8
      for (int kk = 0; kk < 32; kk++) {
        float4 bv = *(const float4*)&lds_w[kk * 128 + tc * 4];
        float av = lds_b[row][kk];
        gh[0] += av * bv.x; gh[1] += av * bv.y;
        gh[2] += av * bv.z; gh[3] += av * bv.w;
      }
      __syncthreads();
    }
    if (g == 0) {
      #pragma unroll
      for (int j = 0; j < 4; j++)
        rv[j] = sigmoidf_fast(gi[j] + gh[j] + bhr[tc * 4 + j]);
    } else if (g == 1) {
      #pragma unroll
      for (int j = 0; j < 4; j++)
        zv[j] = sigmoidf_fast(gi[j] + gh[j] + bhz[tc * 4 + j]);
    } else {
      float4 bel = *(const float4*)&beliefs[(size_t)(r0 + row) * HID + tc * 4];
      float b4[4] = {bel.x, bel.y, bel.z, bel.w};
      #pragma unroll
      for (int j = 0; j < 4; j++) {
        float pre = gi[j] + rv[j] * (gh[j] + bhn[tc * 4 + j]);
        float nv = tanhf_fast(pre);
        nb[j] = (1.f - zv[j]) * nv + zv[j] * b4[j];
      }
    }
  }

  // new_beliefs out + stash for logits
  {
    float4 o = {nb[0], nb[1], nb[2], nb[3]};
    *(float4*)&out[(size_t)NACT * A_N + (size_t)(r0 + row) * HID + tc * 4] = o;
    #pragma unroll
    for (int j = 0; j < 4; j++) lds_x[row][tc * 4 + j] = nb[j];
  }
  lds_w[t] = Wout[t];
  lds_w[t + 256] = Wout[t + 256];
  lds_w[t + 512] = Wout[t + 512];
  if (t < NACT) lds_bo[t] = bout[t];
  __syncthreads();
  if (t < 8 * NACT) {
    int r = t / NACT, c = t % NACT;
    float a = lds_bo[c];
    #pragma unroll 8
    for (int k = 0; k < HID; k++) a += lds_x[r][k] * lds_w[k * NACT + c];
    out[(size_t)(r0 + r) * NACT + c] = a;
  }
}

// ---------------------------------------------------------------------------
extern "C" void kernel_launch(void* const* d_in, const int* in_sizes, int n_in,
                              void* d_out, int out_size, void* d_ws, size_t ws_size,
                              hipStream_t stream) {
  const float* obs     = (const float*)d_in[0];
  const float* beliefs = (const float*)d_in[1];
  const float* W1      = (const float*)d_in[2];
  const float* b1      = (const float*)d_in[3];
  const float* W2      = (const float*)d_in[4];
  const float* b2      = (const float*)d_in[5];
  const float* Wb      = (const float*)d_in[6];
  const float* bb      = (const float*)d_in[7];
  const float* Wg      = (const float*)d_in[8];
  const float* bg      = (const float*)d_in[9];
  const float* Wir     = (const float*)d_in[10];
  const float* Wiz     = (const float*)d_in[11];
  const float* Win     = (const float*)d_in[12];
  const float* Whr     = (const float*)d_in[13];
  const float* bhr     = (const float*)d_in[14];
  const float* Whz     = (const float*)d_in[15];
  const float* bhz     = (const float*)d_in[16];
  const float* Whn     = (const float*)d_in[17];
  const float* bhn     = (const float*)d_in[18];
  const float* Wout    = (const float*)d_in[19];
  const float* bout    = (const float*)d_in[20];
  float* out = (float*)d_out;

  // ws layout (bytes): h2 2MB | bp 1MB | bpT 1MB | ctxp(bf16) 16MB | sums(bf16) 256KB
  // total 21233664 B == round-1 footprint
  char* ws = (char*)d_ws;
  float*          h2   = (float*)(ws);
  unsigned short* bp   = (unsigned short*)(ws + 2097152);
  unsigned short* bpT  = (unsigned short*)(ws + 3145728);
  unsigned short* ctxp = (unsigned short*)(ws + 4194304);
  unsigned short* sums = (unsigned short*)(ws + 4194304 + 16777216);

  hipLaunchKernelGGL(k1_obs_mlp, dim3(512), dim3(256), 0, stream, obs, W1, b1, W2, b2, h2);
  hipLaunchKernelGGL(k2a_bp, dim3(256), dim3(256), 0, stream, beliefs, Wb, bb, bp, bpT);
  hipLaunchKernelGGL(k2b_attn, dim3((A_N / QROWS) * SPLIT / 4), dim3(256), 0, stream, bp, bpT, ctxp, sums);
  hipLaunchKernelGGL(k3_gru, dim3(A_N / 8), dim3(256), 0, stream, beliefs, h2, ctxp, sums,
                     Wg, bg, Wir, Wiz, Win, Whr, bhr, Whz, bhz, Whn, bhn, Wout, bout, out);
}

// Round 3
// 209.295 us; speedup vs baseline: 1.6300x; 1.4687x over previous
//
#include <hip/hip_runtime.h>

#define A_N 8192
#define OBS_D 520
#define EMB 64
#define HID 128
#define NACT 6
#define SPLIT 16

typedef short bf16x8 __attribute__((ext_vector_type(8)));
typedef _Float16 half8 __attribute__((ext_vector_type(8)));
typedef float f32x4 __attribute__((ext_vector_type(4)));
typedef unsigned short u16;
typedef unsigned int u32;

#define MFMA_BF(a,b,c) __builtin_amdgcn_mfma_f32_16x16x32_bf16(a,b,c,0,0,0)
#define MFMA_FH(a,b,c) __builtin_amdgcn_mfma_f32_16x16x32_f16(a,b,c,0,0,0)

__device__ inline u32 fbits(float f){ union{float f; u32 u;}v; v.f=f; return v.u; }
__device__ inline float fval(u32 u){ union{u32 u; float f;}v; v.u=u; return v.f; }
__device__ inline u16 f2bf(float f){ u32 u=fbits(f); u += 0x7fffu + ((u>>16)&1u); return (u16)(u>>16); }
__device__ inline float bf2f(u16 h){ return fval(((u32)h)<<16); }
// pack trunc-bf16(pe), trunc-bf16(po) into one dword (pe in low short)
__device__ inline u32 pk_bf(float pe, float po){
  return __builtin_amdgcn_perm(fbits(po), fbits(pe), 0x07060302u);
}
__device__ inline float sigmoidf_fast(float x){
  x = fminf(fmaxf(x, -30.f), 30.f);
  return 1.f / (1.f + __expf(-x));
}
__device__ inline float tanhf_fast(float x){
  x = fminf(fmaxf(x, -15.f), 15.f);
  float e = __expf(-2.f*x);
  return (1.f - e) / (1.f + e);
}

// exp2 constant: (1/sqrt(64)) * log2(e) = 0.125 * 1.4426950408889634
#define EXP2C 0.18033688011112042f

// ---------------------------------------------------------------------------
// kPrep: transpose+convert weights. block=64. grid 1088.
//  b<896: WT[mi][c][k] f16 of {Wg,Wir,Wiz,Win,Whr,Whz,Whn} (each 128x128)
//  896..959:  W1T f16 [64][544] (k>=520 zero-padded)
//  960..1023: W2T f16 [64][64]
//  1024..1087: WbT bf16 [64][128]
// ---------------------------------------------------------------------------
__global__ __launch_bounds__(64) void kPrep(
    const float* __restrict__ Wg, const float* __restrict__ Wir,
    const float* __restrict__ Wiz, const float* __restrict__ Win,
    const float* __restrict__ Whr, const float* __restrict__ Whz,
    const float* __restrict__ Whn, const float* __restrict__ W1,
    const float* __restrict__ W2, const float* __restrict__ Wb,
    _Float16* __restrict__ WT, _Float16* __restrict__ W1T,
    _Float16* __restrict__ W2T, u16* __restrict__ WbT)
{
  const int b = blockIdx.x, lane = threadIdx.x;
  if (b < 896) {
    const int mi = b >> 7, c = b & 127;
    const float* src = mi==0?Wg: mi==1?Wir: mi==2?Wiz: mi==3?Win: mi==4?Whr: mi==5?Whz: Whn;
    _Float16* dst = WT + (size_t)mi*16384 + (size_t)c*128;
    dst[lane]      = (_Float16)src[(size_t)lane*128 + c];
    dst[lane + 64] = (_Float16)src[(size_t)(lane+64)*128 + c];
  } else if (b < 960) {
    const int c = b - 896;
    #pragma unroll
    for (int i = 0; i < 9; i++) {
      const int k = i*64 + lane;
      if (k < 544)
        W1T[(size_t)c*544 + k] = (k < OBS_D) ? (_Float16)W1[(size_t)k*EMB + c] : (_Float16)0.f;
    }
  } else if (b < 1024) {
    const int c = b - 960;
    W2T[(size_t)c*64 + lane] = (_Float16)W2[(size_t)lane*EMB + c];
  } else {
    const int c = b - 1024;
    WbT[(size_t)c*128 + lane]      = f2bf(Wb[(size_t)lane*EMB + c]);
    WbT[(size_t)c*128 + lane + 64] = f2bf(Wb[(size_t)(lane+64)*EMB + c]);
  }
}

// ---------------------------------------------------------------------------
// kA2: bp = bf16(beliefs@Wb + bb), row-major [8192][64] + transposed [64][8192].
// MFMA bf16, 1 wave per block, 16 rows each, 512 blocks.
// ---------------------------------------------------------------------------
__global__ __launch_bounds__(64) void kA2(
    const float* __restrict__ beliefs, const u16* __restrict__ WbT,
    const float* __restrict__ bb, u16* __restrict__ bp, u16* __restrict__ bpT)
{
  const int lane = threadIdx.x, m = lane & 15, quad = lane >> 4;
  const int r0 = blockIdx.x * 16;
  f32x4 c[4];
  #pragma unroll
  for (int ct = 0; ct < 4; ct++) c[ct] = (f32x4){0.f,0.f,0.f,0.f};

  #pragma unroll
  for (int s = 0; s < 4; s++) {
    const int k0 = s*32;
    const float* ap = beliefs + (size_t)(r0+m)*HID + k0 + quad*8;
    float4 a0 = *(const float4*)ap;
    float4 a1 = *(const float4*)(ap + 4);
    union { u16 e[8]; bf16x8 v; } av;
    av.e[0]=f2bf(a0.x); av.e[1]=f2bf(a0.y); av.e[2]=f2bf(a0.z); av.e[3]=f2bf(a0.w);
    av.e[4]=f2bf(a1.x); av.e[5]=f2bf(a1.y); av.e[6]=f2bf(a1.z); av.e[7]=f2bf(a1.w);
    #pragma unroll
    for (int ct = 0; ct < 4; ct++) {
      bf16x8 bw = *(const bf16x8*)(WbT + (size_t)(ct*16+m)*128 + k0 + quad*8);
      c[ct] = MFMA_BF(av.v, bw, c[ct]);
    }
  }
  #pragma unroll
  for (int ct = 0; ct < 4; ct++) {
    const int col = ct*16 + m;
    const float bbv = bb[col];
    u16 e[4];
    #pragma unroll
    for (int r = 0; r < 4; r++) e[r] = f2bf(c[ct][r] + bbv);
    #pragma unroll
    for (int r = 0; r < 4; r++)
      bp[(size_t)(r0 + quad*4 + r)*EMB + col] = e[r];
    const u32 u01 = (u32)e[0] | ((u32)e[1] << 16);
    const u32 u23 = (u32)e[2] | ((u32)e[3] << 16);
    uint2 pkv; pkv.x = u01; pkv.y = u23;
    *(uint2*)(bpT + (size_t)col*A_N + r0 + quad*4) = pkv;
  }
}

// ---------------------------------------------------------------------------
// kM: mega kernel. blocks <1024: flash attention (S^T formulation);
//     blocks 1024..1151: obs-MLP via f16 MFMA (16 rows/wave, 64 rows/block).
// Attention wave: 32 q-rows x one 512-key split. Per 64-key tile:
//   S^T = K·Q^T (C-layout gives 4 j-contiguous P values/lane -> ds_write_b64),
//   LDS round-trip with wave-private buffer + lgkmcnt wait (no barrier),
//   PV: A=P (LDS b128), B=V (bpT rows). V issued at top, K(t+1) prefetched
//   after QK so PV waits vmcnt(8) and the prefetch stays in flight.
// ---------------------------------------------------------------------------
__global__ __launch_bounds__(256) void kM(
    const u16* __restrict__ bp, const u16* __restrict__ bpT,
    u16* __restrict__ ctxp, float* __restrict__ sums,
    const float* __restrict__ obs, const _Float16* __restrict__ W1T,
    const float* __restrict__ b1, const _Float16* __restrict__ W2T,
    const float* __restrict__ b2, _Float16* __restrict__ h2f)
{
  __shared__ __align__(16) u16 P[4][2][16*72];   // 18432 B, wave-private halves
  const int lane = threadIdx.x & 63;
  const int wid  = threadIdx.x >> 6;
  const int m = lane & 15, quad = lane >> 4;

  if (blockIdx.x < 1024) {
    const int w = blockIdx.x * 4 + wid;
    const int split = w >> 8;        // co-resident waves stream same keys
    const int qt = w & 255;
    const int q0 = qt * 32;

    bf16x8 qa[2][2];
    #pragma unroll
    for (int f = 0; f < 2; f++) {
      const u16* qr = bp + (size_t)(q0 + f*16 + m)*EMB + quad*8;
      qa[f][0] = *(const bf16x8*)(qr);
      qa[f][1] = *(const bf16x8*)(qr + 32);
    }
    f32x4 oacc[2][4];
    #pragma unroll
    for (int f = 0; f < 2; f++)
      #pragma unroll
      for (int d = 0; d < 4; d++) oacc[f][d] = (f32x4){0.f,0.f,0.f,0.f};
    float rowsum[2] = {0.f, 0.f};

    const int kbeg = split * (A_N / SPLIT);
    const int kend = kbeg + (A_N / SPLIT);

    bf16x8 kb[4][2];
    #pragma unroll
    for (int jt = 0; jt < 4; jt++) {
      const u16* kr = bp + (size_t)(kbeg + jt*16 + m)*EMB + quad*8;
      kb[jt][0] = *(const bf16x8*)(kr);
      kb[jt][1] = *(const bf16x8*)(kr + 32);
    }
    u16* Pl[2] = { &P[wid][0][0], &P[wid][1][0] };

    for (int k0 = kbeg; k0 < kend; k0 += 64) {
      // V loads at top: latency hidden under QK+exp+pack
      bf16x8 vb[4][2];
      #pragma unroll
      for (int dt = 0; dt < 4; dt++) {
        const u16* vr = bpT + (size_t)(dt*16+m)*A_N + k0 + quad*8;
        vb[dt][0] = *(const bf16x8*)(vr);
        vb[dt][1] = *(const bf16x8*)(vr + 32);
      }
      // QK (S^T) + exp + pack + wave-private LDS write
      #pragma unroll
      for (int jt = 0; jt < 4; jt++) {
        #pragma unroll
        for (int f = 0; f < 2; f++) {
          f32x4 s = (f32x4){0.f,0.f,0.f,0.f};
          s = MFMA_BF(kb[jt][0], qa[f][0], s);
          s = MFMA_BF(kb[jt][1], qa[f][1], s);
          float p0 = exp2f(s[0]*EXP2C), p1 = exp2f(s[1]*EXP2C);
          float p2 = exp2f(s[2]*EXP2C), p3 = exp2f(s[3]*EXP2C);
          if ((k0 + jt*16) == (q0 + f*16)) {   // wave-uniform: tile holds diagonal
            const int jl = quad*4;
            if (jl + 0 == m) p0 = 0.f;
            if (jl + 1 == m) p1 = 0.f;
            if (jl + 2 == m) p2 = 0.f;
            if (jl + 3 == m) p3 = 0.f;
          }
          rowsum[f] += (p0 + p1) + (p2 + p3);
          uint2 pkv; pkv.x = pk_bf(p0, p1); pkv.y = pk_bf(p2, p3);
          *(uint2*)(Pl[f] + m*72 + jt*16 + quad*4) = pkv;
        }
      }
      // prefetch next K tile (stays in flight through PV: vb issued first)
      if (k0 + 64 < kend) {
        #pragma unroll
        for (int jt = 0; jt < 4; jt++) {
          const u16* kr = bp + (size_t)(k0 + 64 + jt*16 + m)*EMB + quad*8;
          kb[jt][0] = *(const bf16x8*)(kr);
          kb[jt][1] = *(const bf16x8*)(kr + 32);
        }
      }
      // wave-local write->read ordering (no block barrier)
      asm volatile("s_waitcnt lgkmcnt(0)" ::: "memory");
      bf16x8 pa[2][2];
      #pragma unroll
      for (int f = 0; f < 2; f++) {
        pa[f][0] = *(const bf16x8*)(Pl[f] + m*72 + quad*8);
        pa[f][1] = *(const bf16x8*)(Pl[f] + m*72 + 32 + quad*8);
      }
      #pragma unroll
      for (int dt = 0; dt < 4; dt++)
        #pragma unroll
        for (int f = 0; f < 2; f++) {
          oacc[f][dt] = MFMA_BF(pa[f][0], vb[dt][0], oacc[f][dt]);
          oacc[f][dt] = MFMA_BF(pa[f][1], vb[dt][1], oacc[f][dt]);
        }
    }

    // rowsum: q = m; reduce across the 4 lanes sharing m (xor 16, 32)
    #pragma unroll
    for (int f = 0; f < 2; f++) {
      float v = rowsum[f];
      v += __shfl_xor(v, 16, 64);
      v += __shfl_xor(v, 32, 64);
      rowsum[f] = v;
    }
    if (lane < 16) {
      sums[(size_t)split*A_N + q0 + lane]      = rowsum[0];
      sums[(size_t)split*A_N + q0 + 16 + lane] = rowsum[1];
    }
    #pragma unroll
    for (int f = 0; f < 2; f++) {
      const size_t base = ((size_t)split*A_N + q0 + f*16) * EMB;
      #pragma unroll
      for (int dt = 0; dt < 4; dt++)
        #pragma unroll
        for (int r = 0; r < 4; r++)
          ctxp[base + (size_t)(quad*4+r)*EMB + dt*16 + m] = f2bf(oacc[f][dt][r]);
    }
  } else {
    // ---------------- obs-MLP via f16 MFMA ----------------
    const int r0 = (blockIdx.x - 1024) * 64 + wid * 16;
    f32x4 oa[4];
    #pragma unroll
    for (int ct = 0; ct < 4; ct++) oa[ct] = (f32x4){0.f,0.f,0.f,0.f};

    for (int s = 0; s < 17; s++) {
      const int k0 = s * 32;
      union { _Float16 e[8]; half8 v; } af;
      if (s < 16) {
        const float* ap = obs + (size_t)(r0+m)*OBS_D + k0 + quad*8;
        float4 a0 = *(const float4*)ap;
        float4 a1 = *(const float4*)(ap + 4);
        af.e[0]=(_Float16)a0.x; af.e[1]=(_Float16)a0.y; af.e[2]=(_Float16)a0.z; af.e[3]=(_Float16)a0.w;
        af.e[4]=(_Float16)a1.x; af.e[5]=(_Float16)a1.y; af.e[6]=(_Float16)a1.z; af.e[7]=(_Float16)a1.w;
      } else {
        #pragma unroll
        for (int j = 0; j < 8; j++) af.e[j] = (_Float16)0.f;
        if (quad == 0) {   // k = 512..519 valid (W1T rows 520.. are zero)
          const float* ap = obs + (size_t)(r0+m)*OBS_D + 512;
          float4 a0 = *(const float4*)ap;
          float4 a1 = *(const float4*)(ap + 4);
          af.e[0]=(_Float16)a0.x; af.e[1]=(_Float16)a0.y; af.e[2]=(_Float16)a0.z; af.e[3]=(_Float16)a0.w;
          af.e[4]=(_Float16)a1.x; af.e[5]=(_Float16)a1.y; af.e[6]=(_Float16)a1.z; af.e[7]=(_Float16)a1.w;
        }
      }
      #pragma unroll
      for (int ct = 0; ct < 4; ct++) {
        half8 bw = *(const half8*)(W1T + (size_t)(ct*16+m)*544 + k0 + quad*8);
        oa[ct] = MFMA_FH(af.v, bw, oa[ct]);
      }
    }
    // h1 = relu(oa + b1) -> wave-private LDS (f16, row-major [16][72])
    _Float16* H1 = (_Float16*)&P[wid][0][0];
    #pragma unroll
    for (int ct = 0; ct < 4; ct++) {
      const float b1v = b1[ct*16 + m];
      #pragma unroll
      for (int r = 0; r < 4; r++) {
        float v = fmaxf(oa[ct][r] + b1v, 0.f);
        H1[(quad*4+r)*72 + ct*16 + m] = (_Float16)v;
      }
    }
    asm volatile("s_waitcnt lgkmcnt(0)" ::: "memory");
    f32x4 ob[4];
    #pragma unroll
    for (int ct = 0; ct < 4; ct++) ob[ct] = (f32x4){0.f,0.f,0.f,0.f};
    #pragma unroll
    for (int s2 = 0; s2 < 2; s2++) {
      half8 ah = *(const half8*)(H1 + m*72 + s2*32 + quad*8);
      #pragma unroll
      for (int ct = 0; ct < 4; ct++) {
        half8 bw = *(const half8*)(W2T + (size_t)(ct*16+m)*64 + s2*32 + quad*8);
        ob[ct] = MFMA_FH(ah, bw, ob[ct]);
      }
    }
    #pragma unroll
    for (int ct = 0; ct < 4; ct++) {
      const float b2v = b2[ct*16 + m];
      #pragma unroll
      for (int r = 0; r < 4; r++) {
        float v = fmaxf(ob[ct][r] + b2v, 0.f);
        h2f[(size_t)(r0 + quad*4 + r)*EMB + ct*16 + m] = (_Float16)v;
      }
    }
  }
}

// ---------------------------------------------------------------------------
// k3: GRU + logits via f16 MFMA. 16 rows/block, 512 blocks, 4 waves/block
// (wave owns 2 col-tiles = 32 of 128 cols). Weights read from pre-transposed
// f16 WT arrays straight from global (L1/L2-hot).
// ---------------------------------------------------------------------------
__global__ __launch_bounds__(256) void k3_gru(
    const float* __restrict__ beliefs, const _Float16* __restrict__ h2f,
    const u16* __restrict__ ctxp, const float* __restrict__ sums,
    const _Float16* __restrict__ WT,
    const float* __restrict__ bg, const float* __restrict__ bhr,
    const float* __restrict__ bhz, const float* __restrict__ bhn,
    const float* __restrict__ Wout, const float* __restrict__ bout,
    float* __restrict__ out)
{
  __shared__ _Float16 xf[16][136];     // x = [h2|ctx]; reused for new_beliefs
  __shared__ _Float16 belf[16][136];
  __shared__ _Float16 gruf[16][136];
  __shared__ float invs[16];
  const int t = threadIdx.x;
  const int lane = t & 63, wid = t >> 6;
  const int m = lane & 15, quad = lane >> 4;
  const int r0 = blockIdx.x * 16;

  // Phase 0: fill belf, xf(h2 part), ctx accumulate, sums
  {
    const int row = t >> 4, seg = t & 15;
    const float* bpR = beliefs + (size_t)(r0+row)*HID + seg*8;
    float4 a0 = *(const float4*)bpR;
    float4 a1 = *(const float4*)(bpR + 4);
    union { _Float16 e[8]; half8 v; } hb;
    hb.e[0]=(_Float16)a0.x; hb.e[1]=(_Float16)a0.y; hb.e[2]=(_Float16)a0.z; hb.e[3]=(_Float16)a0.w;
    hb.e[4]=(_Float16)a1.x; hb.e[5]=(_Float16)a1.y; hb.e[6]=(_Float16)a1.z; hb.e[7]=(_Float16)a1.w;
    *(half8*)&belf[row][seg*8] = hb.v;
  }
  float ctxa[8];
  const int crow = t >> 3, cdg = t & 7;
  if (t < 128) {
    half8 hv = *(const half8*)(h2f + (size_t)(r0+crow)*EMB + cdg*8);
    *(half8*)&xf[crow][cdg*8] = hv;
    #pragma unroll
    for (int d = 0; d < 8; d++) ctxa[d] = 0.f;
    #pragma unroll
    for (int sp = 0; sp < SPLIT; sp++) {
      uint4 u = *(const uint4*)(ctxp + ((size_t)sp*A_N + r0 + crow)*EMB + cdg*8);
      ctxa[0] += fval(u.x << 16); ctxa[1] += fval(u.x & 0xffff0000u);
      ctxa[2] += fval(u.y << 16); ctxa[3] += fval(u.y & 0xffff0000u);
      ctxa[4] += fval(u.z << 16); ctxa[5] += fval(u.z & 0xffff0000u);
      ctxa[6] += fval(u.w << 16); ctxa[7] += fval(u.w & 0xffff0000u);
    }
  }
  if (t < 16) {
    float s = 0.f;
    #pragma unroll
    for (int sp = 0; sp < SPLIT; sp++) s += sums[(size_t)sp*A_N + r0 + t];
    invs[t] = 1.f / s;
  }
  __syncthreads();
  if (t < 128) {
    const float iv = invs[crow];
    union { _Float16 e[8]; half8 v; } hc;
    #pragma unroll
    for (int d = 0; d < 8; d++) hc.e[d] = (_Float16)(ctxa[d] * iv);
    *(half8*)&xf[crow][64 + cdg*8] = hc.v;
  }
  __syncthreads();

  // Phase 1: gru_in = x @ Wg + bg  (wave: col-tiles wid*2, wid*2+1)
  const _Float16* WgT = WT;
  f32x4 g[2];
  g[0] = (f32x4){0.f,0.f,0.f,0.f}; g[1] = (f32x4){0.f,0.f,0.f,0.f};
  #pragma unroll
  for (int s = 0; s < 4; s++) {
    half8 ax = *(const half8*)&xf[m][s*32 + quad*8];
    #pragma unroll
    for (int ci = 0; ci < 2; ci++) {
      const int ct = wid*2 + ci;
      half8 bw = *(const half8*)(WgT + (size_t)(ct*16+m)*128 + s*32 + quad*8);
      g[ci] = MFMA_FH(ax, bw, g[ci]);
    }
  }
  #pragma unroll
  for (int ci = 0; ci < 2; ci++) {
    const int col = (wid*2+ci)*16 + m;
    const float bgv = bg[col];
    #pragma unroll
    for (int r = 0; r < 4; r++)
      gruf[quad*4+r][col] = (_Float16)(g[ci][r] + bgv);
  }
  __syncthreads();

  // Phase 2: gates
  f32x4 RV[2], ZV[2];
  #pragma unroll
  for (int gidx = 0; gidx < 3; gidx++) {
    const _Float16* WiTg = WT + (size_t)(1+gidx)*16384;
    const _Float16* WhTg = WT + (size_t)(4+gidx)*16384;
    f32x4 gi[2], gh[2];
    gi[0]=(f32x4){0.f,0.f,0.f,0.f}; gi[1]=(f32x4){0.f,0.f,0.f,0.f};
    gh[0]=(f32x4){0.f,0.f,0.f,0.f}; gh[1]=(f32x4){0.f,0.f,0.f,0.f};
    #pragma unroll
    for (int s = 0; s < 4; s++) {
      half8 ag = *(const half8*)&gruf[m][s*32 + quad*8];
      half8 ab = *(const half8*)&belf[m][s*32 + quad*8];
      #pragma unroll
      for (int ci = 0; ci < 2; ci++) {
        const int ct = wid*2 + ci;
        half8 bi = *(const half8*)(WiTg + (size_t)(ct*16+m)*128 + s*32 + quad*8);
        half8 bh = *(const half8*)(WhTg + (size_t)(ct*16+m)*128 + s*32 + quad*8);
        gi[ci] = MFMA_FH(ag, bi, gi[ci]);
        gh[ci] = MFMA_FH(ab, bh, gh[ci]);
      }
    }
    if (gidx == 0) {
      #pragma unroll
      for (int ci = 0; ci < 2; ci++) {
        const float bv = bhr[(wid*2+ci)*16 + m];
        #pragma unroll
        for (int r = 0; r < 4; r++) RV[ci][r] = sigmoidf_fast(gi[ci][r] + gh[ci][r] + bv);
      }
    } else if (gidx == 1) {
      #pragma unroll
      for (int ci = 0; ci < 2; ci++) {
        const float bv = bhz[(wid*2+ci)*16 + m];
        #pragma unroll
        for (int r = 0; r < 4; r++) ZV[ci][r] = sigmoidf_fast(gi[ci][r] + gh[ci][r] + bv);
      }
    } else {
      #pragma unroll
      for (int ci = 0; ci < 2; ci++) {
        const int col = (wid*2+ci)*16 + m;
        const float bv = bhn[col];
        #pragma unroll
        for (int r = 0; r < 4; r++) {
          const int row = quad*4 + r;
          float bel = beliefs[(size_t)(r0+row)*HID + col];
          float pre = gi[ci][r] + RV[ci][r] * (gh[ci][r] + bv);
          float nv = tanhf_fast(pre);
          float nb = (1.f - ZV[ci][r]) * nv + ZV[ci][r] * bel;
          out[(size_t)NACT*A_N + (size_t)(r0+row)*HID + col] = nb;
          xf[row][col] = (_Float16)nb;   // xf no longer read as x; reuse for logits
        }
      }
    }
  }
  __syncthreads();

  // Phase 3: logits
  if (t < 16*NACT) {
    const int row = t / NACT, c = t % NACT;
    float a = bout[c];
    #pragma unroll 8
    for (int k = 0; k < HID; k++)
      a += (float)xf[row][k] * Wout[(size_t)k*NACT + c];
    out[(size_t)(r0+row)*NACT + c] = a;
  }
}

// ---------------------------------------------------------------------------
extern "C" void kernel_launch(void* const* d_in, const int* in_sizes, int n_in,
                              void* d_out, int out_size, void* d_ws, size_t ws_size,
                              hipStream_t stream) {
  const float* obs     = (const float*)d_in[0];
  const float* beliefs = (const float*)d_in[1];
  const float* W1      = (const float*)d_in[2];
  const float* b1      = (const float*)d_in[3];
  const float* W2      = (const float*)d_in[4];
  const float* b2      = (const float*)d_in[5];
  const float* Wb      = (const float*)d_in[6];
  const float* bb      = (const float*)d_in[7];
  const float* Wg      = (const float*)d_in[8];
  const float* bg      = (const float*)d_in[9];
  const float* Wir     = (const float*)d_in[10];
  const float* Wiz     = (const float*)d_in[11];
  const float* Win     = (const float*)d_in[12];
  const float* Whr     = (const float*)d_in[13];
  const float* bhr     = (const float*)d_in[14];
  const float* Whz     = (const float*)d_in[15];
  const float* bhz     = (const float*)d_in[16];
  const float* Whn     = (const float*)d_in[17];
  const float* bhn     = (const float*)d_in[18];
  const float* Wout    = (const float*)d_in[19];
  const float* bout    = (const float*)d_in[20];
  float* out = (float*)d_out;

  // ws layout (bytes), total 20,770,816 <= 21,233,664 (round-1 footprint):
  // h2f f16 1MB | bp 1MB | bpT 1MB | ctxp bf16 16MB | sums f32 512KB |
  // WT f16 7x32KB | W1T f16 68KB+pad | W2T f16 8KB | WbT bf16 16KB
  char* ws = (char*)d_ws;
  _Float16* h2f  = (_Float16*)(ws);
  u16*      bp   = (u16*)(ws + 1048576);
  u16*      bpT  = (u16*)(ws + 2097152);
  u16*      ctxp = (u16*)(ws + 3145728);
  float*    sums = (float*)(ws + 19922944);
  _Float16* WT   = (_Float16*)(ws + 20447232);
  _Float16* W1T  = (_Float16*)(ws + 20676608);
  _Float16* W2T  = (_Float16*)(ws + 20746240);
  u16*      WbT  = (u16*)(ws + 20754432);

  hipLaunchKernelGGL(kPrep, dim3(1088), dim3(64), 0, stream,
                     Wg, Wir, Wiz, Win, Whr, Whz, Whn, W1, W2, Wb, WT, W1T, W2T, WbT);
  hipLaunchKernelGGL(kA2, dim3(512), dim3(64), 0, stream, beliefs, WbT, bb, bp, bpT);
  hipLaunchKernelGGL(kM, dim3(1152), dim3(256), 0, stream,
                     bp, bpT, ctxp, sums, obs, W1T, b1, W2T, b2, h2f);
  hipLaunchKernelGGL(k3_gru, dim3(512), dim3(256), 0, stream,
                     beliefs, h2f, ctxp, sums, WT, bg, bhr, bhz, bhn, Wout, bout, out);
}